// Round 4
// baseline (340.449 us; speedup 1.0000x reference)
//
#include <hip/hip_runtime.h>

typedef unsigned short u16;
typedef unsigned int   u32;
typedef float f32x4 __attribute__((ext_vector_type(4)));
typedef __bf16 bf16x8 __attribute__((ext_vector_type(8)));
typedef unsigned short u16x8 __attribute__((ext_vector_type(8)));
typedef unsigned short u16x4 __attribute__((ext_vector_type(4)));

#define PP   6400
#define HH   80
#define WW   80
#define KC   256
#define CH   324
#define CPAD 384
#define PW   82          // padded spatial width
#define PPIX (PW*PW)     // 6724 padded pixels
#define NPOOL 2176       // pooled cells padded (1600+400+100 -> 2176)

__device__ inline float b2f(u16 u) { union { u32 i; float f; } v; v.i = ((u32)u) << 16; return v.f; }
__device__ inline u16 f2b(float f) {
    union { u32 i; float f; } v; v.f = f;
    u32 r = v.i + 0x7fffu + ((v.i >> 16) & 1u);
    return (u16)(r >> 16);
}

// async global->LDS, 16B per lane; LDS dst = wave-uniform base + lane*16
__device__ __forceinline__ void gload16(const void* g, void* l) {
    __builtin_amdgcn_global_load_lds((const __attribute__((address_space(1))) void*)g,
                                     (__attribute__((address_space(3))) void*)l, 16, 0, 0);
}

// ---------------- prep: fA[p][c] = bf16(f[c][p]) via LDS tile transpose ----------------
__global__ __launch_bounds__(256) void prep_f(const float* __restrict__ f0,
                                              const float* __restrict__ f1,
                                              u16* __restrict__ fA, u16* __restrict__ fB) {
    __shared__ float tile[64][65];
    int p0 = blockIdx.x * 64, c0 = blockIdx.y * 64;
    const float* src = blockIdx.z ? f1 : f0;
    u16* dst = blockIdx.z ? fB : fA;
    int tid = threadIdx.x;
#pragma unroll
    for (int it = 0; it < 16; ++it) {
        int idx = tid + it * 256;
        int cc = idx >> 6, pp = idx & 63;
        tile[cc][pp] = src[(size_t)(c0 + cc) * PP + p0 + pp];
    }
    __syncthreads();
#pragma unroll
    for (int it = 0; it < 16; ++it) {
        int idx = tid + it * 256;
        int pp = idx >> 6, cc = idx & 63;
        dst[(size_t)(p0 + pp) * KC + c0 + cc] = f2b(tile[cc][pp]);
    }
}

// ---------------- prep weights: wT[tap][co][ci] = w[tap][ci][co], zero-padded to 384 ----------------
__global__ __launch_bounds__(384) void prep_w(const float* __restrict__ w1,
                                              const float* __restrict__ w2,
                                              u16* __restrict__ wT1, u16* __restrict__ wT2) {
    int tap = blockIdx.x / CPAD;
    int co  = blockIdx.x % CPAD;
    int ci  = threadIdx.x;
    const float* w = blockIdx.y ? w2 : w1;
    u16* wT = blockIdx.y ? wT2 : wT1;
    float v = 0.f;
    if (co < CH && ci < CH) v = w[((size_t)tap * CH + ci) * CH + co];
    wT[((size_t)tap * CPAD + co) * CPAD + ci] = f2b(v);
}

__global__ __launch_bounds__(384) void prep_b(const float* __restrict__ b1,
                                              const float* __restrict__ b2,
                                              float* __restrict__ b1p, float* __restrict__ b2p) {
    int t = threadIdx.x;
    b1p[t] = t < CH ? b1[t] : 0.f;
    b2p[t] = t < CH ? b2[t] : 0.f;
}

// ---------------- zero the 1-pixel halo of feat and t1 (ws is re-poisoned every call) ----------------
__global__ __launch_bounds__(384) void zero_border(u16* __restrict__ feat, u16* __restrict__ t1) {
    int bi = blockIdx.x, dir = blockIdx.y;
    int pix;
    if (bi < 82) pix = bi;                        // top row
    else if (bi < 164) pix = 81 * PW + (bi - 82); // bottom row
    else if (bi < 244) pix = (bi - 164 + 1) * PW; // left col
    else pix = (bi - 244 + 1) * PW + 81;          // right col
    size_t off = ((size_t)dir * PPIX + pix) * CPAD + threadIdx.x;
    feat[off] = 0;
    t1[off] = 0;
}

// ---------------- pooled features: pbar L1 (1600 cells) ----------------
__global__ __launch_bounds__(256) void poolA(const u16* __restrict__ fA,
                                             const u16* __restrict__ fB,
                                             u16* __restrict__ pbarA,
                                             u16* __restrict__ pbarB) {
    int cell = blockIdx.x;
    const u16* src = blockIdx.y ? fA : fB;   // y=0: pooled B (for dir0), y=1: pooled A (for dir1)
    u16* dst = blockIdx.y ? pbarA : pbarB;
    int cy = cell / 40, cx = cell % 40;
    int p00 = (2 * cy) * 80 + 2 * cx;
    int k = threadIdx.x;
    float v = 0.25f * (b2f(src[(size_t)p00 * KC + k]) + b2f(src[(size_t)(p00 + 1) * KC + k]) +
                       b2f(src[(size_t)(p00 + 80) * KC + k]) + b2f(src[(size_t)(p00 + 81) * KC + k]));
    dst[(size_t)cell * KC + k] = f2b(v);
}

// ---------------- pooled features: L2 (400) + L3 (100), both from L1 ----------------
__global__ __launch_bounds__(256) void poolB(u16* __restrict__ pbarA, u16* __restrict__ pbarB) {
    int bi = blockIdx.x;
    u16* pb = blockIdx.y ? pbarA : pbarB;
    int k = threadIdx.x;
    if (bi < 400) {
        int cy = bi / 20, cx = bi % 20;
        int b0 = (2 * cy) * 40 + 2 * cx;
        float v = 0.25f * (b2f(pb[(size_t)b0 * KC + k]) + b2f(pb[(size_t)(b0 + 1) * KC + k]) +
                           b2f(pb[(size_t)(b0 + 40) * KC + k]) + b2f(pb[(size_t)(b0 + 41) * KC + k]));
        pb[(size_t)(1600 + bi) * KC + k] = f2b(v);
    } else {
        int j = bi - 400;
        int cy = j / 10, cx = j % 10;
        float s = 0.f;
#pragma unroll
        for (int a = 0; a < 4; ++a)
#pragma unroll
            for (int b = 0; b < 4; ++b)
                s += b2f(pb[(size_t)((4 * cy + a) * 40 + 4 * cx + b) * KC + k]);
        pb[(size_t)(2000 + j) * KC + k] = f2b(s * 0.0625f);
    }
}

// ---------------- banded corr GEMM: only diagonal-band 128x128 tiles (|p-q|<=324) ----------------
__global__ __launch_bounds__(256) void gemm_band(const u16* __restrict__ fA,
                                                 const u16* __restrict__ fB,
                                                 u16* __restrict__ corr01,
                                                 u16* __restrict__ corr10) {
    int n0t = (int)blockIdx.x + (int)blockIdx.y - 3;
    if (n0t < 0 || n0t >= 50) return;
    __shared__ __align__(16) char smem[128 * 136 * 2];   // As+Bs (32KB) overlap trans (34KB)
    u16* As = (u16*)smem;
    u16* Bs = As + 128 * 64;
    u16* trans = (u16*)smem;
    const int TS = 136;
    int tid = threadIdx.x;
    int wave = tid >> 6, lane = tid & 63;
    int quad = lane >> 4, l16 = lane & 15;
    int lrow = lane >> 3, lchunk = lane & 7;
    int sc = lchunk ^ (lrow & 7);
    int sw = l16 & 7;
    int wr = (wave >> 1) * 64, wc = (wave & 1) * 64;
    int m0 = blockIdx.x * 128, n0 = n0t * 128;
    f32x4 acc[4][4] = {};

    for (int k0 = 0; k0 < KC; k0 += 64) {
        __syncthreads();
#pragma unroll
        for (int i = 0; i < 4; ++i) {
            int row = i * 32 + wave * 8 + lrow;
            gload16(&fA[(size_t)(m0 + row) * KC + k0 + sc * 8], &As[(i * 32 + wave * 8) * 64]);
            gload16(&fB[(size_t)(n0 + row) * KC + k0 + sc * 8], &Bs[(i * 32 + wave * 8) * 64]);
        }
        __syncthreads();
#pragma unroll
        for (int ki = 0; ki < 2; ++ki) {
            bf16x8 af[4], bfr[4];
#pragma unroll
            for (int mi = 0; mi < 4; ++mi) {
                int r = wr + mi * 16 + l16;
                af[mi] = *(const bf16x8*)(&As[r * 64 + (((ki * 4 + quad) ^ sw) * 8)]);
            }
#pragma unroll
            for (int ni = 0; ni < 4; ++ni) {
                int r = wc + ni * 16 + l16;
                bfr[ni] = *(const bf16x8*)(&Bs[r * 64 + (((ki * 4 + quad) ^ sw) * 8)]);
            }
#pragma unroll
            for (int mi = 0; mi < 4; ++mi)
#pragma unroll
                for (int ni = 0; ni < 4; ++ni)
                    acc[mi][ni] = __builtin_amdgcn_mfma_f32_16x16x32_bf16(af[mi], bfr[ni], acc[mi][ni], 0, 0, 0);
        }
    }
#pragma unroll
    for (int mi = 0; mi < 4; ++mi)
#pragma unroll
        for (int ni = 0; ni < 4; ++ni)
#pragma unroll
            for (int rr = 0; rr < 4; ++rr) {
                int row = m0 + wr + mi * 16 + quad * 4 + rr;
                int col = n0 + wc + ni * 16 + l16;
                corr01[(size_t)row * PP + col] = f2b(acc[mi][ni][rr]);
            }
    __syncthreads();
#pragma unroll
    for (int mi = 0; mi < 4; ++mi)
#pragma unroll
        for (int ni = 0; ni < 4; ++ni) {
            int c = wc + ni * 16 + l16;
            int rbase = wr + mi * 16 + quad * 4;
#pragma unroll
            for (int h = 0; h < 2; ++h) {
                u32 pk = (u32)f2b(acc[mi][ni][2 * h]) | ((u32)f2b(acc[mi][ni][2 * h + 1]) << 16);
                *(u32*)(&trans[c * TS + rbase + 2 * h]) = pk;
            }
        }
    __syncthreads();
#pragma unroll
    for (int it = 0; it < 8; ++it) {
        int c = it * 16 + (tid >> 4);
        int r8 = (tid & 15) * 8;
        u16x8 v = *(const u16x8*)(&trans[c * TS + r8]);
        *(u16x8*)(&corr10[(size_t)(n0 + c) * PP + m0 + r8]) = v;
    }
}

// ---------------- pooled-corr GEMM: pc[dir][p][cell] = A[p] . pbar[cell], N=2176 ----------------
__global__ __launch_bounds__(256) void gemm_pool(const u16* __restrict__ fA,
                                                 const u16* __restrict__ fB,
                                                 const u16* __restrict__ pbarA,
                                                 const u16* __restrict__ pbarB,
                                                 u16* __restrict__ pc) {
    int dir = blockIdx.z;
    const u16* A = dir ? fB : fA;
    const u16* Bp = dir ? pbarA : pbarB;
    __shared__ __align__(16) u16 As[128 * 64];
    __shared__ __align__(16) u16 Bs[128 * 64];
    int tid = threadIdx.x;
    int wave = tid >> 6, lane = tid & 63;
    int quad = lane >> 4, l16 = lane & 15;
    int lrow = lane >> 3, lchunk = lane & 7;
    int sc = lchunk ^ (lrow & 7);
    int sw = l16 & 7;
    int wr = (wave >> 1) * 64, wc = (wave & 1) * 64;
    int m0 = blockIdx.x * 128, n0 = blockIdx.y * 128;
    f32x4 acc[4][4] = {};

    for (int k0 = 0; k0 < KC; k0 += 64) {
        __syncthreads();
#pragma unroll
        for (int i = 0; i < 4; ++i) {
            int row = i * 32 + wave * 8 + lrow;
            gload16(&A[(size_t)(m0 + row) * KC + k0 + sc * 8], &As[(i * 32 + wave * 8) * 64]);
            gload16(&Bp[(size_t)(n0 + row) * KC + k0 + sc * 8], &Bs[(i * 32 + wave * 8) * 64]);
        }
        __syncthreads();
#pragma unroll
        for (int ki = 0; ki < 2; ++ki) {
            bf16x8 af[4], bfr[4];
#pragma unroll
            for (int mi = 0; mi < 4; ++mi) {
                int r = wr + mi * 16 + l16;
                af[mi] = *(const bf16x8*)(&As[r * 64 + (((ki * 4 + quad) ^ sw) * 8)]);
            }
#pragma unroll
            for (int ni = 0; ni < 4; ++ni) {
                int r = wc + ni * 16 + l16;
                bfr[ni] = *(const bf16x8*)(&Bs[r * 64 + (((ki * 4 + quad) ^ sw) * 8)]);
            }
#pragma unroll
            for (int mi = 0; mi < 4; ++mi)
#pragma unroll
                for (int ni = 0; ni < 4; ++ni)
                    acc[mi][ni] = __builtin_amdgcn_mfma_f32_16x16x32_bf16(af[mi], bfr[ni], acc[mi][ni], 0, 0, 0);
        }
    }
#pragma unroll
    for (int mi = 0; mi < 4; ++mi)
#pragma unroll
        for (int ni = 0; ni < 4; ++ni)
#pragma unroll
            for (int rr = 0; rr < 4; ++rr) {
                int row = m0 + wr + mi * 16 + quad * 4 + rr;
                int col = n0 + wc + ni * 16 + l16;
                pc[((size_t)dir * PP + row) * NPOOL + col] = f2b(acc[mi][ni][rr]);
            }
}

// ---------------- lookup: gather band (L0) + pooled-corr row (L1-3) ----------------
__global__ __launch_bounds__(384) void lookup(const u16* __restrict__ corr01,
                                              const u16* __restrict__ corr10,
                                              const u16* __restrict__ pc,
                                              u16* __restrict__ feat) {
    __shared__ __align__(16) u16 pcrow[NPOOL];
    int p = blockIdx.x, dir = blockIdx.y;
    int px = p % WW, py = p / WW;
    int tid = threadIdx.x;
    if (tid < NPOOL / 8)
        *(u16x8*)(&pcrow[tid * 8]) = *(const u16x8*)(&pc[((size_t)dir * PP + p) * NPOOL + tid * 8]);
    float l0v = 0.f;
    if (tid < 81) {
        int dx = tid / 9 - 4, dy = tid % 9 - 4;
        int x = px + dx, y = py + dy;
        if ((unsigned)x < (unsigned)WW && (unsigned)y < (unsigned)HH)
            l0v = b2f((dir ? corr10 : corr01)[(size_t)p * PP + y * WW + x]);
    }
    __syncthreads();
    int ch = tid;
    float val = 0.f;
    if (ch < CH) {
        int lvl = ch / 81, i = ch % 81;
        if (lvl == 0) {
            val = l0v;
        } else {
            int dx = i / 9 - 4, dy = i % 9 - 4;
            int wl = WW >> lvl;
            int base = (lvl == 1) ? 0 : (lvl == 2) ? 1600 : 2000;
            float inv = 1.0f / (float)(2 << lvl);
            float xc = (float)(2 * px + 1) * inv - 0.5f + (float)dx;
            float yc = (float)(2 * py + 1) * inv - 0.5f + (float)dy;
            float x0f = floorf(xc), y0f = floorf(yc);
            int x0 = (int)x0f, y0 = (int)y0f;
            float wx = xc - x0f, wy = yc - y0f;
#pragma unroll
            for (int cy = 0; cy < 2; ++cy)
#pragma unroll
                for (int cx = 0; cx < 2; ++cx) {
                    int xi = x0 + cx, yi = y0 + cy;
                    if ((unsigned)xi < (unsigned)wl && (unsigned)yi < (unsigned)wl) {
                        float wgt = (cx ? wx : 1.f - wx) * (cy ? wy : 1.f - wy);
                        val += b2f(pcrow[base + yi * wl + xi]) * wgt;
                    }
                }
        }
    }
    size_t pix = (size_t)(py + 1) * PW + px + 1;
    feat[((size_t)dir * PPIX + pix) * CPAD + ch] = f2b(val);
}

// ---------------- conv GEMM: 128x128 tile, BK=64, tap-split k=2, fp32 partials ----------------
__global__ __launch_bounds__(256) void conv_gemm(const u16* __restrict__ inFeat,
                                                 const u16* __restrict__ wTt,
                                                 float* __restrict__ partial) {
    int z = blockIdx.z;
    int dir = z >> 1, ks = z & 1;
    const u16* Ain = inFeat + (size_t)dir * PPIX * CPAD;
    __shared__ __align__(16) u16 As[128 * 64];
    __shared__ __align__(16) u16 Bs[128 * 64];
    int tid = threadIdx.x;
    int wave = tid >> 6, lane = tid & 63;
    int quad = lane >> 4, l16 = lane & 15;
    int lrow = lane >> 3, lchunk = lane & 7;
    int sc = lchunk ^ (lrow & 7);
    int sw = l16 & 7;
    int wr = (wave >> 1) * 64, wc = (wave & 1) * 64;
    int m0 = blockIdx.x * 128, n0 = blockIdx.y * 128;
    f32x4 acc[4][4] = {};

    int pixA[4];
#pragma unroll
    for (int i = 0; i < 4; ++i) {
        int m = m0 + i * 32 + wave * 8 + lrow;
        pixA[i] = (m / 80 + 1) * PW + (m % 80) + 1;
    }
    int tap0 = ks ? 4 : 0;
    int nr = ks ? 30 : 24;

    for (int rr2 = 0; rr2 < nr; ++rr2) {
        int tap = tap0 + rr2 / 6, kc = (rr2 % 6) * 64;
        int dpix = (tap / 3 - 1) * PW + (tap % 3) - 1;
        const u16* Wt = wTt + ((size_t)tap * CPAD + n0) * CPAD + kc;
        __syncthreads();
#pragma unroll
        for (int i = 0; i < 4; ++i) {
            gload16(&Ain[(size_t)(pixA[i] + dpix) * CPAD + kc + sc * 8],
                    &As[(i * 32 + wave * 8) * 64]);
            gload16(&Wt[(size_t)(i * 32 + wave * 8 + lrow) * CPAD + sc * 8],
                    &Bs[(i * 32 + wave * 8) * 64]);
        }
        __syncthreads();
#pragma unroll
        for (int ki = 0; ki < 2; ++ki) {
            bf16x8 af[4], bfr[4];
#pragma unroll
            for (int mi = 0; mi < 4; ++mi) {
                int r = wr + mi * 16 + l16;
                af[mi] = *(const bf16x8*)(&As[r * 64 + (((ki * 4 + quad) ^ sw) * 8)]);
            }
#pragma unroll
            for (int ni = 0; ni < 4; ++ni) {
                int r = wc + ni * 16 + l16;
                bfr[ni] = *(const bf16x8*)(&Bs[r * 64 + (((ki * 4 + quad) ^ sw) * 8)]);
            }
#pragma unroll
            for (int mi = 0; mi < 4; ++mi)
#pragma unroll
                for (int ni = 0; ni < 4; ++ni)
                    acc[mi][ni] = __builtin_amdgcn_mfma_f32_16x16x32_bf16(af[mi], bfr[ni], acc[mi][ni], 0, 0, 0);
        }
    }
#pragma unroll
    for (int mi = 0; mi < 4; ++mi)
#pragma unroll
        for (int ni = 0; ni < 4; ++ni)
#pragma unroll
            for (int rr = 0; rr < 4; ++rr) {
                int row = m0 + wr + mi * 16 + quad * 4 + rr;
                int col = n0 + wc + ni * 16 + l16;
                partial[((size_t)z * PP + row) * CPAD + col] = acc[mi][ni][rr];
            }
}

// ---------------- combine partials after conv1: bias + relu -> t1 (bf16, padded) ----------------
__global__ __launch_bounds__(256) void combine1(const float* __restrict__ partial,
                                                const float* __restrict__ bias,
                                                u16* __restrict__ t1) {
    int dir = blockIdx.y;
    int p0 = blockIdx.x * 16;
    int tid = threadIdx.x;
    for (int idx = tid; idx < 16 * 96; idx += 256) {
        int pp = idx / 96, c4 = (idx % 96) * 4;
        int p = p0 + pp;
        f32x4 a = *(const f32x4*)(&partial[((size_t)(dir * 2) * PP + p) * CPAD + c4]);
        f32x4 b = *(const f32x4*)(&partial[((size_t)(dir * 2 + 1) * PP + p) * CPAD + c4]);
        f32x4 bi = *(const f32x4*)(&bias[c4]);
        u16x4 o;
#pragma unroll
        for (int j = 0; j < 4; ++j) {
            float v = a[j] + b[j] + bi[j];
            o[j] = f2b(fmaxf(v, 0.f));
        }
        size_t pix = (size_t)(p / 80 + 1) * PW + (p % 80) + 1;
        *(u16x4*)(&t1[((size_t)dir * PPIX + pix) * CPAD + c4]) = o;
    }
}

// ---------------- combine partials after conv2 + residual + layernorm + transposed out ----------------
__global__ __launch_bounds__(256) void combine2_ln(const float* __restrict__ partial,
                                                   const float* __restrict__ bias,
                                                   const u16* __restrict__ feat,
                                                   const float* __restrict__ g,
                                                   const float* __restrict__ b,
                                                   float* __restrict__ out) {
    int dir = blockIdx.y;
    int p0 = blockIdx.x * 64;
    __shared__ u16 buf[64 * 325];
    __shared__ float mean_s[64], inv_s[64];
    __shared__ float part[64][4][2];
    int tid = threadIdx.x;
    for (int idx = tid; idx < 64 * CH; idx += 256) {
        int pp = idx / CH, c = idx - pp * CH;
        int p = p0 + pp;
        float v = partial[((size_t)(dir * 2) * PP + p) * CPAD + c] +
                  partial[((size_t)(dir * 2 + 1) * PP + p) * CPAD + c] + bias[c];
        v = fmaxf(v, 0.f);
        size_t pix = (size_t)(p / 80 + 1) * PW + (p % 80) + 1;
        v += b2f(feat[((size_t)dir * PPIX + pix) * CPAD + c]);
        buf[pp * 325 + c] = f2b(v);
    }
    __syncthreads();
    {
        int pp = tid >> 2, q = tid & 3;
        float s = 0.f, s2 = 0.f;
        for (int c = q; c < CH; c += 4) { float v = b2f(buf[pp * 325 + c]); s += v; s2 += v * v; }
        part[pp][q][0] = s; part[pp][q][1] = s2;
    }
    __syncthreads();
    if (tid < 64) {
        float s = 0.f, s2 = 0.f;
        for (int q = 0; q < 4; ++q) { s += part[tid][q][0]; s2 += part[tid][q][1]; }
        float m = s / (float)CH;
        float var = s2 / (float)CH - m * m;
        if (var < 0.f) var = 0.f;
        mean_s[tid] = m;
        inv_s[tid] = rsqrtf(var + 1e-5f);
    }
    __syncthreads();
    for (int idx = tid; idx < CH * 64; idx += 256) {
        int c = idx >> 6, pp = idx & 63;
        float v = (b2f(buf[pp * 325 + c]) - mean_s[pp]) * inv_s[pp] * g[c] + b[c];
        out[((size_t)(dir * CH + c)) * PP + p0 + pp] = v;
    }
}

extern "C" void kernel_launch(void* const* d_in, const int* in_sizes, int n_in,
                              void* d_out, int out_size, void* d_ws, size_t ws_size,
                              hipStream_t stream) {
    const float* f0  = (const float*)d_in[0];
    const float* f1  = (const float*)d_in[1];
    const float* w1  = (const float*)d_in[2];
    const float* b1  = (const float*)d_in[3];
    const float* w2  = (const float*)d_in[4];
    const float* b2  = (const float*)d_in[5];
    const float* lng = (const float*)d_in[6];
    const float* lnb = (const float*)d_in[7];
    float* out = (float*)d_out;

    char* ws = (char*)d_ws;
    size_t off = 0;
    auto alloc = [&](size_t bytes) -> char* {
        char* r = ws + off;
        off += (bytes + 511) & ~(size_t)511;
        return r;
    };
    u16* fA     = (u16*)alloc((size_t)PP * KC * 2);
    u16* fB     = (u16*)alloc((size_t)PP * KC * 2);
    u16* corr01 = (u16*)alloc((size_t)PP * PP * 2);    // band region only written
    u16* corr10 = (u16*)alloc((size_t)PP * PP * 2);
    u16* pc     = (u16*)alloc((size_t)2 * PP * NPOOL * 2);
    u16* feat   = (u16*)alloc((size_t)2 * PPIX * CPAD * 2);
    u16* t1     = (u16*)alloc((size_t)2 * PPIX * CPAD * 2);
    u16* pbarA  = (u16*)alloc((size_t)NPOOL * KC * 2);
    u16* pbarB  = (u16*)alloc((size_t)NPOOL * KC * 2);
    u16* wT1    = (u16*)alloc((size_t)9 * CPAD * CPAD * 2);
    u16* wT2    = (u16*)alloc((size_t)9 * CPAD * CPAD * 2);
    float* b1p  = (float*)alloc(CPAD * 4);
    float* b2p  = (float*)alloc(CPAD * 4);
    // conv partials (4 x 6400 x 384 fp32 = 39.3 MB) alias corr01 (82 MB, dead after lookup)
    float* partial = (float*)corr01;

    prep_f<<<dim3(100, 4, 2), 256, 0, stream>>>(f0, f1, fA, fB);
    prep_w<<<dim3(9 * CPAD, 2), 384, 0, stream>>>(w1, w2, wT1, wT2);
    prep_b<<<1, 384, 0, stream>>>(b1, b2, b1p, b2p);
    zero_border<<<dim3(324, 2), 384, 0, stream>>>(feat, t1);
    poolA<<<dim3(1600, 2), 256, 0, stream>>>(fA, fB, pbarA, pbarB);
    poolB<<<dim3(500, 2), 256, 0, stream>>>(pbarA, pbarB);
    gemm_band<<<dim3(50, 7), 256, 0, stream>>>(fA, fB, corr01, corr10);
    gemm_pool<<<dim3(50, 17, 2), 256, 0, stream>>>(fA, fB, pbarA, pbarB, pc);
    lookup<<<dim3(PP, 2), 384, 0, stream>>>(corr01, corr10, pc, feat);
    conv_gemm<<<dim3(50, 3, 4), 256, 0, stream>>>(feat, wT1, partial);
    combine1<<<dim3(400, 2), 256, 0, stream>>>(partial, b1p, t1);
    conv_gemm<<<dim3(50, 3, 4), 256, 0, stream>>>(t1, wT2, partial);
    combine2_ln<<<dim3(100, 2), 256, 0, stream>>>(partial, b2p, feat, lng, lnb, out);
}